// Round 1
// baseline (1131.146 us; speedup 1.0000x reference)
//
#include <hip/hip_runtime.h>
#include <cstddef>
#include <cstdint>

#define N_NODES 12288
#define D_IN    512
#define D_EMB   128
#define D_OUT   64
#define NEDGE   393216

// ---------------------------------------------------------------------------
// init: zero degree histogram + split-K accumulator, detect edge dtype.
// int64 node ids < 12288 -> every odd int32 word of the first 64 ids is 0.
// ---------------------------------------------------------------------------
__global__ __launch_bounds__(256) void init_kernel(const int* __restrict__ ei,
    int* __restrict__ flag, int* __restrict__ deg, float* __restrict__ cacc)
{
  int idx = blockIdx.x * 256 + threadIdx.x;
  if (idx < N_NODES) deg[idx] = 0;
  if (idx < D_IN * D_EMB) cacc[idx] = 0.f;
  if (idx == 0) {
    int ok = 1;
    for (int t = 0; t < 64; ++t) ok &= (ei[2 * t + 1] == 0);
    *flag = ok;  // 1 => data is int64, 0 => int32
  }
}

__global__ __launch_bounds__(256) void edge_deg(const int* __restrict__ ei,
    const int* __restrict__ flag, int* __restrict__ deg)
{
  int e = blockIdx.x * 256 + threadIdx.x;
  if (e >= NEDGE) return;
  int dst = (*flag) ? ei[2 * (NEDGE + e)] : ei[NEDGE + e];
  atomicAdd(&deg[dst], 1);
}

// single-block exclusive scan of deg[12288] -> rp, cursor
__global__ __launch_bounds__(256) void scan_deg(const int* __restrict__ deg,
    int* __restrict__ rp, int* __restrict__ cursor)
{
  __shared__ int sums[256];
  constexpr int C = N_NODES / 256;  // 48
  int t = threadIdx.x;
  int base = t * C;
  int local[C];
  int s = 0;
  for (int i = 0; i < C; ++i) { local[i] = deg[base + i]; s += local[i]; }
  sums[t] = s;
  __syncthreads();
  for (int off = 1; off < 256; off <<= 1) {
    int v = (t >= off) ? sums[t - off] : 0;
    __syncthreads();
    sums[t] += v;
    __syncthreads();
  }
  int prefix = (t == 0) ? 0 : sums[t - 1];
  for (int i = 0; i < C; ++i) {
    rp[base + i] = prefix;
    cursor[base + i] = prefix;
    prefix += local[i];
  }
  if (t == 255) rp[N_NODES] = prefix;
}

__global__ __launch_bounds__(256) void edge_scatter(const int* __restrict__ ei,
    const int* __restrict__ flag, int* __restrict__ cursor, int* __restrict__ csr)
{
  int e = blockIdx.x * 256 + threadIdx.x;
  if (e >= NEDGE) return;
  int is64 = *flag;
  int src = is64 ? ei[2 * e] : ei[e];
  int dst = is64 ? ei[2 * (NEDGE + e)] : ei[NEDGE + e];
  int p = atomicAdd(&cursor[dst], 1);
  csr[p] = src;
}

// ---------------------------------------------------------------------------
// Generic NT GEMM: C[m][n] = act(sum_k A[m*K+k]*B[n*K+k] + bias[n])
// BM=BN=64, BK=32, 256 threads, 4x4 per thread. M%64==N%64==K%32==0 assumed.
// ---------------------------------------------------------------------------
template<int ACT>
__global__ __launch_bounds__(256) void gemm_nt64(const float* __restrict__ A,
    const float* __restrict__ B, const float* __restrict__ bias,
    float* __restrict__ C, int M, int N, int K, int ldc)
{
  __shared__ float As[32][64];  // [k][m]
  __shared__ float Bs[32][64];  // [k][n]
  int m0 = blockIdx.x * 64, n0 = blockIdx.y * 64;
  int tid = threadIdx.x;
  int tx = tid & 15, ty = tid >> 4;
  float acc[4][4] = {};
  for (int k0 = 0; k0 < K; k0 += 32) {
#pragma unroll
    for (int p = 0; p < 2; ++p) {
      int idx = tid + p * 256;
      int row = idx >> 3;   // 8 float4 per 32-wide k row
      int kq  = idx & 7;
      float4 va = *(const float4*)(A + (size_t)(m0 + row) * K + k0 + kq * 4);
      As[kq*4+0][row] = va.x; As[kq*4+1][row] = va.y;
      As[kq*4+2][row] = va.z; As[kq*4+3][row] = va.w;
      float4 vb = *(const float4*)(B + (size_t)(n0 + row) * K + k0 + kq * 4);
      Bs[kq*4+0][row] = vb.x; Bs[kq*4+1][row] = vb.y;
      Bs[kq*4+2][row] = vb.z; Bs[kq*4+3][row] = vb.w;
    }
    __syncthreads();
#pragma unroll
    for (int k = 0; k < 32; ++k) {
      float a[4], b[4];
      *(float4*)a = *(const float4*)&As[k][ty * 4];
      *(float4*)b = *(const float4*)&Bs[k][tx * 4];
#pragma unroll
      for (int r = 0; r < 4; ++r)
#pragma unroll
        for (int c = 0; c < 4; ++c)
          acc[r][c] = fmaf(a[r], b[c], acc[r][c]);
    }
    __syncthreads();
  }
#pragma unroll
  for (int r = 0; r < 4; ++r) {
    int m = m0 + ty * 4 + r;
    float4 o;
    float* po = &o.x;
#pragma unroll
    for (int c = 0; c < 4; ++c) {
      float v = acc[r][c];
      if (bias) v += bias[n0 + tx * 4 + c];
      if (ACT) v = fmaxf(v, 0.f);
      po[c] = v;
    }
    *(float4*)(C + (size_t)m * ldc + n0 + tx * 4) = o;
  }
}

// per-node attention scores: sc_s[i]=dot(g[i],a_src), sc_d[i]=dot(g[i],a_dst)
__global__ __launch_bounds__(256) void scores_kernel(const float* __restrict__ g,
    const float* __restrict__ a_src, const float* __restrict__ a_dst,
    float* __restrict__ sc_s, float* __restrict__ sc_d)
{
  int lane = threadIdx.x & 63;
  int i = blockIdx.x * 4 + (threadIdx.x >> 6);
  float gv = g[(size_t)i * 64 + lane];
  float vs = gv * a_src[lane];
  float vd = gv * a_dst[lane];
#pragma unroll
  for (int off = 32; off; off >>= 1) {
    vs += __shfl_xor(vs, off);
    vd += __shfl_xor(vd, off);
  }
  if (lane == 0) { sc_s[i] = vs; sc_d[i] = vd; }
}

// one wave per destination node: exact segment max/sum softmax + gather-accum
__global__ __launch_bounds__(256) void gat_kernel(const int* __restrict__ rp,
    const int* __restrict__ csr, const float* __restrict__ sc_s,
    const float* __restrict__ sc_d, const float* __restrict__ g,
    const float* __restrict__ b_g, float* __restrict__ h)
{
  int lane = threadIdx.x & 63;
  int i = blockIdx.x * 4 + (threadIdx.x >> 6);
  int beg = rp[i], end = rp[i + 1];
  int deg = end - beg;          // real in-edges; j==deg is the self-loop
  float scd = sc_d[i];
  float mymax = -3.4e38f;
  for (int j = lane; j <= deg; j += 64) {
    int s = (j < deg) ? csr[beg + j] : i;
    float e = sc_s[s] + scd;
    e = (e > 0.f) ? e : 0.2f * e;
    mymax = fmaxf(mymax, e);
  }
#pragma unroll
  for (int off = 32; off; off >>= 1) mymax = fmaxf(mymax, __shfl_xor(mymax, off));
  float sum = 0.f;
  for (int j = lane; j <= deg; j += 64) {
    int s = (j < deg) ? csr[beg + j] : i;
    float e = sc_s[s] + scd;
    e = (e > 0.f) ? e : 0.2f * e;
    sum += __expf(e - mymax);
  }
#pragma unroll
  for (int off = 32; off; off >>= 1) sum += __shfl_xor(sum, off);
  float inv = 1.f / sum;
  float acc = 0.f;   // lane == feature
  for (int j = 0; j <= deg; ++j) {
    int s = (j < deg) ? csr[beg + j] : i;
    float e = sc_s[s] + scd;
    e = (e > 0.f) ? e : 0.2f * e;
    float w = __expf(e - mymax) * inv;
    acc = fmaf(w, g[(size_t)s * 64 + lane], acc);
  }
  h[(size_t)i * 64 + lane] = acc + b_g[lane];
}

// ---------------------------------------------------------------------------
// xt pre-activation: cacc[c][j] += sum_i x[i][c] * W_a1[j][i]  (split-K)
// grid (8 c-tiles, 32 K-chunks of 384), 256 thr, thread tile 4c x 8j
// ---------------------------------------------------------------------------
__global__ __launch_bounds__(256) void xt_splitk(const float* __restrict__ x,
    const float* __restrict__ Wa1, float* __restrict__ cacc)
{
  __shared__ float Xs[32][64];    // [i][c]
  __shared__ float Ws[32][128];   // [i][j]
  int c0 = blockIdx.x * 64;
  int i0 = blockIdx.y * 384;
  int tid = threadIdx.x;
  int txc = tid & 15, txj = tid >> 4;
  float acc[4][8] = {};
  for (int ib = 0; ib < 384; ib += 32) {
#pragma unroll
    for (int p = 0; p < 2; ++p) {    // Xs: 32x64 = 512 float4
      int idx = tid + p * 256;
      int row = idx >> 4, q = idx & 15;
      *(float4*)&Xs[row][q * 4] =
          *(const float4*)(x + (size_t)(i0 + ib + row) * D_IN + c0 + q * 4);
    }
#pragma unroll
    for (int p = 0; p < 4; ++p) {    // Ws: 128 rows x 8 float4 (transposed store)
      int idx = tid + p * 256;
      int j = idx >> 3, q = idx & 7;
      float4 v = *(const float4*)(Wa1 + (size_t)j * N_NODES + i0 + ib + q * 4);
      Ws[q*4+0][j] = v.x; Ws[q*4+1][j] = v.y;
      Ws[q*4+2][j] = v.z; Ws[q*4+3][j] = v.w;
    }
    __syncthreads();
#pragma unroll
    for (int ii = 0; ii < 32; ++ii) {
      float a[4], b[8];
      *(float4*)a = *(const float4*)&Xs[ii][txc * 4];
      *(float4*)&b[0] = *(const float4*)&Ws[ii][txj * 8];
      *(float4*)&b[4] = *(const float4*)&Ws[ii][txj * 8 + 4];
#pragma unroll
      for (int r = 0; r < 4; ++r)
#pragma unroll
        for (int c = 0; c < 8; ++c)
          acc[r][c] = fmaf(a[r], b[c], acc[r][c]);
    }
    __syncthreads();
  }
#pragma unroll
  for (int r = 0; r < 4; ++r)
#pragma unroll
    for (int c = 0; c < 8; ++c)
      atomicAdd(&cacc[(size_t)(c0 + txc * 4 + r) * D_EMB + txj * 8 + c], acc[r][c]);
}

__global__ __launch_bounds__(256) void xt_ep(const float* __restrict__ cacc,
    const float* __restrict__ b_a1, float* __restrict__ xt)
{
  int idx = blockIdx.x * 256 + threadIdx.x;  // 65536
  float v = cacc[idx] + b_a1[idx & 127];
  xt[idx] = fmaxf(v, 0.f);
}

// ---------------------------------------------------------------------------
// s_ = sigmoid(h @ h^T): 128x128 tile per block, K=64 in one LDS pass.
// thread tile 8 rows x (4 + 4) cols to keep LDS b-reads 2-way (free).
// ---------------------------------------------------------------------------
__global__ __launch_bounds__(256) void sig_hht(const float* __restrict__ h,
                                               float* __restrict__ out)
{
  __shared__ float Ha[64][128];  // [k][i]
  __shared__ float Hb[64][128];  // [k][j]
  int i0 = blockIdx.x * 128, j0 = blockIdx.y * 128;
  int tid = threadIdx.x;
  int tx = tid & 15, ty = tid >> 4;
#pragma unroll
  for (int p = 0; p < 8; ++p) {   // 128 rows x 16 float4
    int idx = tid + p * 256;
    int row = idx >> 4, kq = idx & 15;
    float4 va = *(const float4*)(h + (size_t)(i0 + row) * 64 + kq * 4);
    Ha[kq*4+0][row] = va.x; Ha[kq*4+1][row] = va.y;
    Ha[kq*4+2][row] = va.z; Ha[kq*4+3][row] = va.w;
    float4 vb = *(const float4*)(h + (size_t)(j0 + row) * 64 + kq * 4);
    Hb[kq*4+0][row] = vb.x; Hb[kq*4+1][row] = vb.y;
    Hb[kq*4+2][row] = vb.z; Hb[kq*4+3][row] = vb.w;
  }
  __syncthreads();
  float acc[8][8] = {};
#pragma unroll 4
  for (int k = 0; k < 64; ++k) {
    float a[8], b[8];
    *(float4*)&a[0] = *(const float4*)&Ha[k][ty * 8];
    *(float4*)&a[4] = *(const float4*)&Ha[k][ty * 8 + 4];
    *(float4*)&b[0] = *(const float4*)&Hb[k][tx * 4];
    *(float4*)&b[4] = *(const float4*)&Hb[k][64 + tx * 4];
#pragma unroll
    for (int r = 0; r < 8; ++r)
#pragma unroll
      for (int c = 0; c < 8; ++c)
        acc[r][c] = fmaf(a[r], b[c], acc[r][c]);
  }
#pragma unroll
  for (int r = 0; r < 8; ++r) {
    size_t row = (size_t)i0 + ty * 8 + r;
    float4 o0, o1;
    float* p0 = &o0.x; float* p1 = &o1.x;
#pragma unroll
    for (int c = 0; c < 4; ++c) p0[c] = 1.f / (1.f + __expf(-acc[r][c]));
#pragma unroll
    for (int c = 0; c < 4; ++c) p1[c] = 1.f / (1.f + __expf(-acc[r][c + 4]));
    *(float4*)(out + row * N_NODES + j0 + tx * 4) = o0;
    *(float4*)(out + row * N_NODES + j0 + 64 + tx * 4) = o1;
  }
}

// ---------------------------------------------------------------------------
extern "C" void kernel_launch(void* const* d_in, const int* in_sizes, int n_in,
                              void* d_out, int out_size, void* d_ws, size_t ws_size,
                              hipStream_t stream)
{
  const float* x     = (const float*)d_in[0];
  const float* W_s1  = (const float*)d_in[1];
  const float* b_s1  = (const float*)d_in[2];
  const float* W_g   = (const float*)d_in[3];
  const float* a_src = (const float*)d_in[4];
  const float* a_dst = (const float*)d_in[5];
  const float* b_g   = (const float*)d_in[6];
  const float* W_a1  = (const float*)d_in[7];
  const float* b_a1  = (const float*)d_in[8];
  const float* W_a2  = (const float*)d_in[9];
  const float* b_a2  = (const float*)d_in[10];
  const int*   ei    = (const int*)d_in[11];

  float* ws   = (float*)d_ws;
  float* x1   = ws;                          // 12288*128
  float* g    = x1 + (size_t)N_NODES * D_EMB;  // 12288*64
  float* h    = g  + (size_t)N_NODES * D_OUT;  // 12288*64
  float* sc_s = h  + (size_t)N_NODES * D_OUT;  // 12288
  float* sc_d = sc_s + N_NODES;              // 12288
  float* cacc = sc_d + N_NODES;              // 65536
  float* xt   = cacc + D_IN * D_EMB;         // 65536
  float* xa   = xt   + D_IN * D_EMB;         // 32768
  int* ib     = (int*)(xa + D_IN * D_OUT);
  int* flag   = ib;                          // 1 (padded to 64)
  int* deg    = ib + 64;                     // 12288
  int* rp     = deg + N_NODES;               // 12289 (padded to 12352)
  int* cursor = rp + 12352;                  // 12288
  int* csr    = cursor + N_NODES;            // 393216

  float* out_x = (float*)d_out;                       // 12288*512
  float* out_s = out_x + (size_t)N_NODES * D_IN;      // 12288*12288

  // CSR build (independent of GEMM chain)
  init_kernel<<<256, 256, 0, stream>>>(ei, flag, deg, cacc);
  edge_deg<<<NEDGE / 256, 256, 0, stream>>>(ei, flag, deg);
  scan_deg<<<1, 256, 0, stream>>>(deg, rp, cursor);
  edge_scatter<<<NEDGE / 256, 256, 0, stream>>>(ei, flag, cursor, csr);

  // structure branch
  gemm_nt64<1><<<dim3(192, 2), 256, 0, stream>>>(x, W_s1, b_s1, x1,
                                                 N_NODES, D_EMB, D_IN, D_EMB);
  gemm_nt64<0><<<dim3(192, 1), 256, 0, stream>>>(x1, W_g, nullptr, g,
                                                 N_NODES, D_OUT, D_EMB, D_OUT);
  scores_kernel<<<N_NODES / 4, 256, 0, stream>>>(g, a_src, a_dst, sc_s, sc_d);
  gat_kernel<<<N_NODES / 4, 256, 0, stream>>>(rp, csr, sc_s, sc_d, g, b_g, h);

  // attribute branch
  xt_splitk<<<dim3(8, 32), 256, 0, stream>>>(x, W_a1, cacc);
  xt_ep<<<D_IN * D_EMB / 256, 256, 0, stream>>>(cacc, b_a1, xt);
  gemm_nt64<0><<<dim3(8, 1), 256, 0, stream>>>(xt, W_a2, b_a2, xa,
                                               D_IN, D_OUT, D_EMB, D_OUT);

  // outputs
  gemm_nt64<0><<<dim3(192, 8), 256, 0, stream>>>(h, xa, nullptr, out_x,
                                                 N_NODES, D_IN, D_OUT, D_IN);
  sig_hht<<<dim3(96, 96), 256, 0, stream>>>(h, out_s);
}

// Round 2
// 922.078 us; speedup vs baseline: 1.2267x; 1.2267x over previous
//
#include <hip/hip_runtime.h>
#include <cstddef>
#include <cstdint>

#define N_NODES 12288
#define D_IN    512
#define D_EMB   128
#define D_OUT   64
#define NEDGE   393216

typedef __attribute__((ext_vector_type(8))) short short8;
typedef __attribute__((ext_vector_type(4))) float f32x4;

__device__ __forceinline__ ushort f2bf(float f) {
  uint32_t u = __float_as_uint(f);
  u += 0x7fffu + ((u >> 16) & 1u);
  return (ushort)(u >> 16);
}
__device__ __forceinline__ float bf2f(ushort h) {
  return __uint_as_float((uint32_t)h << 16);
}

// ---------------------------------------------------------------------------
// init: zero degree histogram, detect edge dtype.
// int64 node ids < 12288 -> every odd int32 word of the first 64 ids is 0.
// ---------------------------------------------------------------------------
__global__ __launch_bounds__(256) void init_kernel(const int* __restrict__ ei,
    int* __restrict__ flag, int* __restrict__ deg)
{
  int idx = blockIdx.x * 256 + threadIdx.x;
  if (idx < N_NODES) deg[idx] = 0;
  if (idx == 0) {
    int ok = 1;
    for (int t = 0; t < 64; ++t) ok &= (ei[2 * t + 1] == 0);
    *flag = ok;  // 1 => data is int64, 0 => int32
  }
}

__global__ __launch_bounds__(256) void edge_deg(const int* __restrict__ ei,
    const int* __restrict__ flag, int* __restrict__ deg)
{
  int e = blockIdx.x * 256 + threadIdx.x;
  if (e >= NEDGE) return;
  int dst = (*flag) ? ei[2 * (NEDGE + e)] : ei[NEDGE + e];
  atomicAdd(&deg[dst], 1);
}

// single-block exclusive scan of deg[12288] -> rp, cursor
__global__ __launch_bounds__(256) void scan_deg(const int* __restrict__ deg,
    int* __restrict__ rp, int* __restrict__ cursor)
{
  __shared__ int sums[256];
  constexpr int C = N_NODES / 256;  // 48
  int t = threadIdx.x;
  int base = t * C;
  int local[C];
  int s = 0;
  for (int i = 0; i < C; ++i) { local[i] = deg[base + i]; s += local[i]; }
  sums[t] = s;
  __syncthreads();
  for (int off = 1; off < 256; off <<= 1) {
    int v = (t >= off) ? sums[t - off] : 0;
    __syncthreads();
    sums[t] += v;
    __syncthreads();
  }
  int prefix = (t == 0) ? 0 : sums[t - 1];
  for (int i = 0; i < C; ++i) {
    rp[base + i] = prefix;
    cursor[base + i] = prefix;
    prefix += local[i];
  }
  if (t == 255) rp[N_NODES] = prefix;
}

__global__ __launch_bounds__(256) void edge_scatter(const int* __restrict__ ei,
    const int* __restrict__ flag, int* __restrict__ cursor, int* __restrict__ csr)
{
  int e = blockIdx.x * 256 + threadIdx.x;
  if (e >= NEDGE) return;
  int is64 = *flag;
  int src = is64 ? ei[2 * e] : ei[e];
  int dst = is64 ? ei[2 * (NEDGE + e)] : ei[NEDGE + e];
  int p = atomicAdd(&cursor[dst], 1);
  csr[p] = src;
}

// ---------------------------------------------------------------------------
// Generic NT GEMM: C[m][n] = act(sum_k A[m*K+k]*B[n*K+k] + bias[n])
// BM=BN=64, BK=32, 256 threads, 4x4 per thread. M%64==N%64==K%32==0 assumed.
// ---------------------------------------------------------------------------
template<int ACT>
__global__ __launch_bounds__(256) void gemm_nt64(const float* __restrict__ A,
    const float* __restrict__ B, const float* __restrict__ bias,
    float* __restrict__ C, int M, int N, int K, int ldc)
{
  __shared__ float As[32][64];  // [k][m]
  __shared__ float Bs[32][64];  // [k][n]
  int m0 = blockIdx.x * 64, n0 = blockIdx.y * 64;
  int tid = threadIdx.x;
  int tx = tid & 15, ty = tid >> 4;
  float acc[4][4] = {};
  for (int k0 = 0; k0 < K; k0 += 32) {
#pragma unroll
    for (int p = 0; p < 2; ++p) {
      int idx = tid + p * 256;
      int row = idx >> 3;   // 8 float4 per 32-wide k row
      int kq  = idx & 7;
      float4 va = *(const float4*)(A + (size_t)(m0 + row) * K + k0 + kq * 4);
      As[kq*4+0][row] = va.x; As[kq*4+1][row] = va.y;
      As[kq*4+2][row] = va.z; As[kq*4+3][row] = va.w;
      float4 vb = *(const float4*)(B + (size_t)(n0 + row) * K + k0 + kq * 4);
      Bs[kq*4+0][row] = vb.x; Bs[kq*4+1][row] = vb.y;
      Bs[kq*4+2][row] = vb.z; Bs[kq*4+3][row] = vb.w;
    }
    __syncthreads();
#pragma unroll
    for (int k = 0; k < 32; ++k) {
      float a[4], b[4];
      *(float4*)a = *(const float4*)&As[k][ty * 4];
      *(float4*)b = *(const float4*)&Bs[k][tx * 4];
#pragma unroll
      for (int r = 0; r < 4; ++r)
#pragma unroll
        for (int c = 0; c < 4; ++c)
          acc[r][c] = fmaf(a[r], b[c], acc[r][c]);
    }
    __syncthreads();
  }
#pragma unroll
  for (int r = 0; r < 4; ++r) {
    int m = m0 + ty * 4 + r;
    float4 o;
    float* po = &o.x;
#pragma unroll
    for (int c = 0; c < 4; ++c) {
      float v = acc[r][c];
      if (bias) v += bias[n0 + tx * 4 + c];
      if (ACT) v = fmaxf(v, 0.f);
      po[c] = v;
    }
    *(float4*)(C + (size_t)m * ldc + n0 + tx * 4) = o;
  }
}

// per-node attention scores: sc_s[i]=dot(g[i],a_src), sc_d[i]=dot(g[i],a_dst)
__global__ __launch_bounds__(256) void scores_kernel(const float* __restrict__ g,
    const float* __restrict__ a_src, const float* __restrict__ a_dst,
    float* __restrict__ sc_s, float* __restrict__ sc_d)
{
  int lane = threadIdx.x & 63;
  int i = blockIdx.x * 4 + (threadIdx.x >> 6);
  float gv = g[(size_t)i * 64 + lane];
  float vs = gv * a_src[lane];
  float vd = gv * a_dst[lane];
#pragma unroll
  for (int off = 32; off; off >>= 1) {
    vs += __shfl_xor(vs, off);
    vd += __shfl_xor(vd, off);
  }
  if (lane == 0) { sc_s[i] = vs; sc_d[i] = vd; }
}

// one wave per destination node: exact segment max/sum softmax + gather-accum.
// Epilogue also emits bf16 hi/lo split of h for the MFMA h@h^T kernel.
__global__ __launch_bounds__(256) void gat_kernel(const int* __restrict__ rp,
    const int* __restrict__ csr, const float* __restrict__ sc_s,
    const float* __restrict__ sc_d, const float* __restrict__ g,
    const float* __restrict__ b_g, float* __restrict__ h,
    ushort* __restrict__ hhi, ushort* __restrict__ hlo)
{
  int lane = threadIdx.x & 63;
  int i = blockIdx.x * 4 + (threadIdx.x >> 6);
  int beg = rp[i], end = rp[i + 1];
  int deg = end - beg;          // real in-edges; j==deg is the self-loop
  float scd = sc_d[i];
  float mymax = -3.4e38f;
  for (int j = lane; j <= deg; j += 64) {
    int s = (j < deg) ? csr[beg + j] : i;
    float e = sc_s[s] + scd;
    e = (e > 0.f) ? e : 0.2f * e;
    mymax = fmaxf(mymax, e);
  }
#pragma unroll
  for (int off = 32; off; off >>= 1) mymax = fmaxf(mymax, __shfl_xor(mymax, off));
  float sum = 0.f;
  for (int j = lane; j <= deg; j += 64) {
    int s = (j < deg) ? csr[beg + j] : i;
    float e = sc_s[s] + scd;
    e = (e > 0.f) ? e : 0.2f * e;
    sum += __expf(e - mymax);
  }
#pragma unroll
  for (int off = 32; off; off >>= 1) sum += __shfl_xor(sum, off);
  float inv = 1.f / sum;
  float acc = 0.f;   // lane == feature
  for (int j = 0; j <= deg; ++j) {
    int s = (j < deg) ? csr[beg + j] : i;
    float e = sc_s[s] + scd;
    e = (e > 0.f) ? e : 0.2f * e;
    float w = __expf(e - mymax) * inv;
    acc = fmaf(w, g[(size_t)s * 64 + lane], acc);
  }
  float val = acc + b_g[lane];
  size_t o = (size_t)i * 64 + lane;
  h[o] = val;
  ushort hi = f2bf(val);
  hhi[o] = hi;
  hlo[o] = f2bf(val - bf2f(hi));
}

// ---------------------------------------------------------------------------
// xt pre-activation partials: part[chunk][c][j] = sum_{i in chunk} x[i][c]*W_a1[j][i]
// grid (8 c-tiles, 64 chunks of 192), 256 thr, thread tile 4c x 8j. No atomics.
// ---------------------------------------------------------------------------
__global__ __launch_bounds__(256) void xt_splitk(const float* __restrict__ x,
    const float* __restrict__ Wa1, float* __restrict__ part)
{
  __shared__ float Xs[32][64];    // [i][c]
  __shared__ float Ws[32][128];   // [i][j]
  int c0 = blockIdx.x * 64;
  int i0 = blockIdx.y * 192;
  float* pout = part + (size_t)blockIdx.y * (D_IN * D_EMB);
  int tid = threadIdx.x;
  int txc = tid & 15, txj = tid >> 4;
  float acc[4][8] = {};
  for (int ib = 0; ib < 192; ib += 32) {
#pragma unroll
    for (int p = 0; p < 2; ++p) {    // Xs: 32x64 = 512 float4
      int idx = tid + p * 256;
      int row = idx >> 4, q = idx & 15;
      *(float4*)&Xs[row][q * 4] =
          *(const float4*)(x + (size_t)(i0 + ib + row) * D_IN + c0 + q * 4);
    }
#pragma unroll
    for (int p = 0; p < 4; ++p) {    // Ws: 128 rows x 8 float4 (transposed store)
      int idx = tid + p * 256;
      int j = idx >> 3, q = idx & 7;
      float4 v = *(const float4*)(Wa1 + (size_t)j * N_NODES + i0 + ib + q * 4);
      Ws[q*4+0][j] = v.x; Ws[q*4+1][j] = v.y;
      Ws[q*4+2][j] = v.z; Ws[q*4+3][j] = v.w;
    }
    __syncthreads();
#pragma unroll
    for (int ii = 0; ii < 32; ++ii) {
      float a[4], b[8];
      *(float4*)a = *(const float4*)&Xs[ii][txc * 4];
      *(float4*)&b[0] = *(const float4*)&Ws[ii][txj * 8];
      *(float4*)&b[4] = *(const float4*)&Ws[ii][txj * 8 + 4];
#pragma unroll
      for (int r = 0; r < 4; ++r)
#pragma unroll
        for (int c = 0; c < 8; ++c)
          acc[r][c] = fmaf(a[r], b[c], acc[r][c]);
    }
    __syncthreads();
  }
#pragma unroll
  for (int r = 0; r < 4; ++r) {
    float4 o0, o1;
    o0.x = acc[r][0]; o0.y = acc[r][1]; o0.z = acc[r][2]; o0.w = acc[r][3];
    o1.x = acc[r][4]; o1.y = acc[r][5]; o1.z = acc[r][6]; o1.w = acc[r][7];
    size_t off = (size_t)(c0 + txc * 4 + r) * D_EMB + txj * 8;
    *(float4*)&pout[off] = o0;
    *(float4*)&pout[off + 4] = o1;
  }
}

// reduce 64 partial chunks, add bias, relu
__global__ __launch_bounds__(256) void xt_ep(const float* __restrict__ part,
    const float* __restrict__ b_a1, float* __restrict__ xt)
{
  int idx = blockIdx.x * 256 + threadIdx.x;  // 65536
  float v = b_a1[idx & 127];
#pragma unroll 8
  for (int c = 0; c < 64; ++c) v += part[(size_t)c * (D_IN * D_EMB) + idx];
  xt[idx] = fmaxf(v, 0.f);
}

// ---------------------------------------------------------------------------
// s_ = sigmoid(h @ h^T) via bf16 MFMA, 3-term hi/lo split (lo*lo dropped).
// 128x128 per block (2x2 waves of 64x64 = 4x4 mfma tiles). No LDS: fragments
// loaded straight from global (h_hi/h_lo are 1.5 MB, L2-resident).
// 16x16x32 bf16 layouts (m89/m91): A[m=lane&15][k=(lane>>4)*8+j],
// C/D col=lane&15, row=(lane>>4)*4+reg.
// ---------------------------------------------------------------------------
__global__ __launch_bounds__(256) void sig_hht_mfma(const ushort* __restrict__ hhi,
    const ushort* __restrict__ hlo, float* __restrict__ out)
{
  int lane = threadIdx.x & 63;
  int wave = threadIdx.x >> 6;
  int i0 = blockIdx.x * 128 + (wave >> 1) * 64;
  int j0 = blockIdx.y * 128 + (wave & 1) * 64;
  int lm = lane & 15, lk = lane >> 4;
  f32x4 acc[4][4];
#pragma unroll
  for (int r = 0; r < 4; ++r)
#pragma unroll
    for (int c = 0; c < 4; ++c) acc[r][c] = (f32x4){0.f, 0.f, 0.f, 0.f};
#pragma unroll
  for (int ks = 0; ks < 2; ++ks) {
    short8 Ah[4], Al[4], Bh[4], Bl[4];
#pragma unroll
    for (int t = 0; t < 4; ++t) {
      size_t ra = (size_t)(i0 + t * 16 + lm) * 64 + ks * 32 + lk * 8;
      size_t rb = (size_t)(j0 + t * 16 + lm) * 64 + ks * 32 + lk * 8;
      Ah[t] = *(const short8*)(hhi + ra);
      Al[t] = *(const short8*)(hlo + ra);
      Bh[t] = *(const short8*)(hhi + rb);
      Bl[t] = *(const short8*)(hlo + rb);
    }
#pragma unroll
    for (int r = 0; r < 4; ++r)
#pragma unroll
      for (int c = 0; c < 4; ++c) {
        acc[r][c] = __builtin_amdgcn_mfma_f32_16x16x32_bf16(Ah[r], Bh[c], acc[r][c], 0, 0, 0);
        acc[r][c] = __builtin_amdgcn_mfma_f32_16x16x32_bf16(Ah[r], Bl[c], acc[r][c], 0, 0, 0);
        acc[r][c] = __builtin_amdgcn_mfma_f32_16x16x32_bf16(Al[r], Bh[c], acc[r][c], 0, 0, 0);
      }
  }
#pragma unroll
  for (int r = 0; r < 4; ++r)
#pragma unroll
    for (int c = 0; c < 4; ++c) {
#pragma unroll
      for (int q = 0; q < 4; ++q) {
        float v = acc[r][c][q];
        float ex = __expf(-v);
#if __has_builtin(__builtin_amdgcn_rcpf)
        float s = __builtin_amdgcn_rcpf(1.f + ex);
#else
        float s = 1.f / (1.f + ex);
#endif
        out[(size_t)(i0 + r * 16 + lk * 4 + q) * N_NODES + (j0 + c * 16 + lm)] = s;
      }
    }
}

// ---------------------------------------------------------------------------
extern "C" void kernel_launch(void* const* d_in, const int* in_sizes, int n_in,
                              void* d_out, int out_size, void* d_ws, size_t ws_size,
                              hipStream_t stream)
{
  const float* x     = (const float*)d_in[0];
  const float* W_s1  = (const float*)d_in[1];
  const float* b_s1  = (const float*)d_in[2];
  const float* W_g   = (const float*)d_in[3];
  const float* a_src = (const float*)d_in[4];
  const float* a_dst = (const float*)d_in[5];
  const float* b_g   = (const float*)d_in[6];
  const float* W_a1  = (const float*)d_in[7];
  const float* b_a1  = (const float*)d_in[8];
  const float* W_a2  = (const float*)d_in[9];
  const float* b_a2  = (const float*)d_in[10];
  const int*   ei    = (const int*)d_in[11];

  float* ws   = (float*)d_ws;
  float* x1   = ws;                            // 12288*128 = 1572864
  float* g    = x1 + (size_t)N_NODES * D_EMB;  // 12288*64  = 786432
  float* h    = g  + (size_t)N_NODES * D_OUT;  // 786432
  float* sc_s = h  + (size_t)N_NODES * D_OUT;  // 12288
  float* sc_d = sc_s + N_NODES;                // 12288
  float* part = sc_d + N_NODES;                // 64*65536 = 4194304
  float* xt   = part + (size_t)64 * D_IN * D_EMB;  // 65536
  float* xa   = xt + D_IN * D_EMB;             // 32768
  int* ib     = (int*)(xa + D_IN * D_OUT);
  int* flag   = ib;                            // 64 (padded)
  int* deg    = ib + 64;                       // 12288
  int* rp     = deg + N_NODES;                 // 12289 (padded to 12352)
  int* cursor = rp + 12352;                    // 12288
  int* csr    = cursor + N_NODES;              // 393216
  ushort* hhi = (ushort*)(csr + NEDGE);        // 786432
  ushort* hlo = hhi + (size_t)N_NODES * D_OUT; // 786432

  float* out_x = (float*)d_out;                       // 12288*512
  float* out_s = out_x + (size_t)N_NODES * D_IN;      // 12288*12288

  // CSR build (independent of GEMM chain)
  init_kernel<<<48, 256, 0, stream>>>(ei, flag, deg);
  edge_deg<<<NEDGE / 256, 256, 0, stream>>>(ei, flag, deg);
  scan_deg<<<1, 256, 0, stream>>>(deg, rp, cursor);
  edge_scatter<<<NEDGE / 256, 256, 0, stream>>>(ei, flag, cursor, csr);

  // structure branch
  gemm_nt64<1><<<dim3(192, 2), 256, 0, stream>>>(x, W_s1, b_s1, x1,
                                                 N_NODES, D_EMB, D_IN, D_EMB);
  gemm_nt64<0><<<dim3(192, 1), 256, 0, stream>>>(x1, W_g, nullptr, g,
                                                 N_NODES, D_OUT, D_EMB, D_OUT);
  scores_kernel<<<N_NODES / 4, 256, 0, stream>>>(g, a_src, a_dst, sc_s, sc_d);
  gat_kernel<<<N_NODES / 4, 256, 0, stream>>>(rp, csr, sc_s, sc_d, g, b_g,
                                              h, hhi, hlo);

  // attribute branch
  xt_splitk<<<dim3(8, 64), 256, 0, stream>>>(x, W_a1, part);
  xt_ep<<<D_IN * D_EMB / 256, 256, 0, stream>>>(part, b_a1, xt);
  gemm_nt64<0><<<dim3(8, 1), 256, 0, stream>>>(xt, W_a2, b_a2, xa,
                                               D_IN, D_OUT, D_EMB, D_OUT);

  // outputs
  gemm_nt64<0><<<dim3(192, 8), 256, 0, stream>>>(h, xa, nullptr, out_x,
                                                 N_NODES, D_IN, D_OUT, D_IN);
  sig_hht_mfma<<<dim3(96, 96), 256, 0, stream>>>(hhi, hlo, out_s);
}